// Round 1
// baseline (320.715 us; speedup 1.0000x reference)
//
#include <hip/hip_runtime.h>
#include <hip/hip_bf16.h>
#include <math.h>

// Problem constants
#define DD 1024   // D
#define HH 4096   // H
#define EE 8      // experts
#define MTOK 4096 // B*S tokens
#define MROWS 8192 // MTOK*K rows of the packed GEMM A operand

typedef __attribute__((ext_vector_type(8))) short bf16x8;
typedef __attribute__((ext_vector_type(4))) float f32x4;

__device__ __forceinline__ unsigned short f2bf(float x){
  __hip_bfloat16 h = __float2bfloat16(x);
  return *reinterpret_cast<unsigned short*>(&h);
}

__device__ __forceinline__ void gload16(const void* g, void* l){
  __builtin_amdgcn_global_load_lds((__attribute__((address_space(1))) void*)g,
                                   (__attribute__((address_space(3))) void*)l,
                                   16, 0, 0);
}

// ---------------- W -> bf16 ----------------
__global__ void cvt_w_kernel(const float4* __restrict__ W4, ushort4* __restrict__ Wb4){
  int i = blockIdx.x * 256 + threadIdx.x;   // covers H*D/4 = 1,048,576 exactly
  float4 v = W4[i];
  ushort4 o;
  o.x = f2bf(v.x); o.y = f2bf(v.y); o.z = f2bf(v.z); o.w = f2bf(v.w);
  Wb4[i] = o;
}

// ---------------- column stats of W (f64) ----------------
__global__ void colstats_part_kernel(const float* __restrict__ W,
                                     double* __restrict__ pmean, double* __restrict__ pm2){
  int d  = (blockIdx.x & 3) * 256 + threadIdx.x; // 0..1023
  int hc = blockIdx.x >> 2;                      // 0..7
  double s = 0.0, s2 = 0.0;
  for (int h = hc * 512; h < (hc + 1) * 512; ++h){
    double w = (double)W[h * DD + d];
    s += w; s2 += w * w;
  }
  pmean[hc * DD + d] = s;
  pm2[hc * DD + d]   = s2;
}

__global__ void colstats_final_kernel(const double* __restrict__ pmean,
                                      const double* __restrict__ pm2,
                                      double* __restrict__ cmean, double* __restrict__ cvar){
  int d = blockIdx.x * 256 + threadIdx.x; // 4 blocks x 256
  double s = 0.0, s2 = 0.0;
  for (int c = 0; c < 8; ++c){ s += pmean[c * DD + d]; s2 += pm2[c * DD + d]; }
  double m = s / (double)HH;
  cmean[d] = m;
  cvar[d]  = s2 / (double)HH - m * m;  // unbiased=False variance of column d
}

__global__ void biasmean_kernel(const float* __restrict__ bias, double* __restrict__ bmean){
  __shared__ double red[256];
  double s = 0.0;
  for (int h = threadIdx.x; h < HH; h += 256) s += (double)bias[h];
  red[threadIdx.x] = s;
  __syncthreads();
  for (int k = 128; k > 0; k >>= 1){
    if (threadIdx.x < k) red[threadIdx.x] += red[threadIdx.x + k];
    __syncthreads();
  }
  if (threadIdx.x == 0) *bmean = red[0] / (double)HH;
}

// ---------------- router (f64) + build packed A operand ----------------
__global__ void router_kernel(const float* __restrict__ x,
                              const float* __restrict__ alpha,
                              const float* __restrict__ beta,
                              const double* __restrict__ cmean,
                              const double* __restrict__ cvar,
                              const double* __restrict__ bmeanp,
                              unsigned short* __restrict__ Xs,
                              float2* __restrict__ wpair){
  int t = blockIdx.x;                    // token
  const float* xt = x + (size_t)t * DD;
  int tid = threadIdx.x, lane = tid & 63, wv = tid >> 6;

  double mu[EE], s2[EE];
  #pragma unroll
  for (int e = 0; e < EE; ++e){ mu[e] = 0.0; s2[e] = 0.0; }

  float xv[4];
  #pragma unroll
  for (int r = 0; r < 4; ++r){
    int d = tid + r * 256;
    float xf = xt[d];
    xv[r] = xf;
    double xd = (double)xf, x2 = xd * xd;
    double cm = cmean[d], cv = cvar[d];
    #pragma unroll
    for (int e = 0; e < EE; ++e){
      double a = (double)alpha[e * DD + d];
      double b = (double)beta[e * DD + d];
      mu[e] += xd * (a * cm + b);
      s2[e] += x2 * (a * a * cv);
    }
  }

  // wave reduce (64 lanes)
  #pragma unroll
  for (int off = 32; off > 0; off >>= 1){
    #pragma unroll
    for (int e = 0; e < EE; ++e){
      mu[e] += __shfl_down(mu[e], off);
      s2[e] += __shfl_down(s2[e], off);
    }
  }
  __shared__ double redmu[4][EE], reds2[4][EE];
  if (lane == 0){
    #pragma unroll
    for (int e = 0; e < EE; ++e){ redmu[wv][e] = mu[e]; reds2[wv][e] = s2[e]; }
  }
  __syncthreads();

  __shared__ int se1, se2;
  if (tid == 0){
    double bm = *bmeanp;
    double lg[EE];
    #pragma unroll
    for (int e = 0; e < EE; ++e){
      double m = redmu[0][e] + redmu[1][e] + redmu[2][e] + redmu[3][e] + bm;
      double v = reds2[0][e] + reds2[1][e] + reds2[2][e] + reds2[3][e] + 1e-8;
      lg[e] = erf(m / (sqrt(2.0) * sqrt(v)));
    }
    // top-2, ties -> lower index (jax.lax.top_k semantics)
    int e1 = 0;
    for (int e = 1; e < EE; ++e) if (lg[e] > lg[e1]) e1 = e;
    int e2 = -1;
    for (int e = 0; e < EE; ++e){
      if (e == e1) continue;
      if (e2 < 0 || lg[e] > lg[e2]) e2 = e;
    }
    double ex = exp(lg[e2] - lg[e1]);        // v2 <= v1, stable softmax
    float w1 = (float)(1.0 / (1.0 + ex));
    float w2 = (float)(ex / (1.0 + ex));
    se1 = e1; se2 = e2;
    wpair[t] = make_float2(w1, w2);
  }
  __syncthreads();
  int e1 = se1, e2 = se2;

  // rows 2t, 2t+1 of packed A: x .* alpha[e1], x .* alpha[e2]  (bf16)
  #pragma unroll
  for (int r = 0; r < 4; ++r){
    int d = tid + r * 256;
    Xs[(size_t)(2 * t)     * DD + d] = f2bf(xv[r] * alpha[e1 * DD + d]);
    Xs[(size_t)(2 * t + 1) * DD + d] = f2bf(xv[r] * alpha[e2 * DD + d]);
  }
}

// ---------------- GEMM: C[8192,4096] = Xs @ Wb^T, fused relu+bias+combine ----------------
#define BM 128
#define BN 128
#define BK 32

__global__ __launch_bounds__(256) void gemm_kernel(const unsigned short* __restrict__ Xs,
                                                   const unsigned short* __restrict__ Wb,
                                                   const float* __restrict__ bias,
                                                   const float2* __restrict__ wpair,
                                                   float* __restrict__ out){
  __shared__ __align__(16) unsigned short As[BM * BK]; // 8 KB
  __shared__ __align__(16) unsigned short Bs[BN * BK]; // 8 KB

  int tid = threadIdx.x;
  int lane = tid & 63;
  int wv = tid >> 6;
  int wr = wv >> 1, wc = wv & 1;

  int bm0 = (blockIdx.x >> 5) * BM;  // 64 M-tiles
  int bn0 = (blockIdx.x & 31) * BN;  // 32 N-tiles

  // staging: each thread loads 16B; LDS linear fill
  int arow = tid >> 2;         // 0..63
  int acol = (tid & 3) * 8;    // element offset in K
  const unsigned short* Ag = Xs + (size_t)(bm0 + arow) * DD + acol;
  const unsigned short* Bg = Wb + (size_t)(bn0 + arow) * DD + acol;
  unsigned short* Asl = As + tid * 8;        // byte off = tid*16
  unsigned short* Bsl = Bs + tid * 8;

  f32x4 acc[4][4] = {};

  int l15 = lane & 15;
  int kb  = (lane >> 4) * 8;   // element offset within BK

  for (int kt = 0; kt < DD / BK; ++kt){
    int k0 = kt * BK;
    gload16(Ag + k0,            Asl);
    gload16(Ag + 64 * DD + k0,  Asl + 64 * BK);
    gload16(Bg + k0,            Bsl);
    gload16(Bg + 64 * DD + k0,  Bsl + 64 * BK);
    __syncthreads();   // drains vmcnt -> tiles ready

    bf16x8 af[4], bfr[4];
    #pragma unroll
    for (int mi = 0; mi < 4; ++mi)
      af[mi] = *(const bf16x8*)(As + (wr * 64 + mi * 16 + l15) * BK + kb);
    #pragma unroll
    for (int ni = 0; ni < 4; ++ni)
      bfr[ni] = *(const bf16x8*)(Bs + (wc * 64 + ni * 16 + l15) * BK + kb);

    #pragma unroll
    for (int mi = 0; mi < 4; ++mi)
      #pragma unroll
      for (int ni = 0; ni < 4; ++ni)
        acc[mi][ni] = __builtin_amdgcn_mfma_f32_16x16x32_bf16(af[mi], bfr[ni], acc[mi][ni], 0, 0, 0);

    __syncthreads();   // compute done before next stage overwrites
  }

  // epilogue: rows 2t (j even) and 2t+1 (j odd) are lane-local -> fuse combine
  #pragma unroll
  for (int mi = 0; mi < 4; ++mi){
    int rbase = wr * 64 + mi * 16 + ((lane >> 4) << 2);
    #pragma unroll
    for (int jp = 0; jp < 2; ++jp){
      int gm = bm0 + rbase + jp * 2;  // even
      int t = gm >> 1;
      float2 w = wpair[t];
      #pragma unroll
      for (int ni = 0; ni < 4; ++ni){
        int gh = bn0 + wc * 64 + ni * 16 + l15;
        float bz = bias[gh];
        float v0 = acc[mi][ni][jp * 2]     + bz;
        float v1 = acc[mi][ni][jp * 2 + 1] + bz;
        out[(size_t)t * HH + gh] = w.x * fmaxf(v0, 0.f) + w.y * fmaxf(v1, 0.f);
      }
    }
  }
}

extern "C" void kernel_launch(void* const* d_in, const int* in_sizes, int n_in,
                              void* d_out, int out_size, void* d_ws, size_t ws_size,
                              hipStream_t stream) {
  const float* x     = (const float*)d_in[0];
  const float* W     = (const float*)d_in[1];
  const float* bias  = (const float*)d_in[2];
  const float* alpha = (const float*)d_in[3];
  const float* beta  = (const float*)d_in[4];
  float* out = (float*)d_out;

  char* ws = (char*)d_ws;
  unsigned short* Wb = (unsigned short*)ws;                    // 8 MB
  unsigned short* Xs = (unsigned short*)(ws + (8u << 20));     // 16 MB
  float2* wpair      = (float2*)(ws + (24u << 20));            // 32 KB
  double* cmean      = (double*)(ws + (24u << 20) + (64u << 10)); // 8 KB
  double* cvar       = cmean + DD;                             // 8 KB
  double* bmean      = cvar + DD;                              // 8 B
  double* pmean      = (double*)(ws + (25u << 20));            // 64 KB
  double* pm2        = pmean + 8 * DD;                         // 64 KB

  cvt_w_kernel<<<4096, 256, 0, stream>>>((const float4*)W, (ushort4*)Wb);
  colstats_part_kernel<<<32, 256, 0, stream>>>(W, pmean, pm2);
  colstats_final_kernel<<<4, 256, 0, stream>>>(pmean, pm2, cmean, cvar);
  biasmean_kernel<<<1, 256, 0, stream>>>(bias, bmean);
  router_kernel<<<MTOK, 256, 0, stream>>>(x, alpha, beta, cmean, cvar, bmean, Xs, wpair);
  gemm_kernel<<<(MROWS / BM) * (HH / BN), 256, 0, stream>>>(Xs, Wb, bias, wpair, out);
}

// Round 2
// 203.525 us; speedup vs baseline: 1.5758x; 1.5758x over previous
//
#include <hip/hip_runtime.h>
#include <hip/hip_bf16.h>
#include <math.h>

// Problem constants
#define DD 1024   // D
#define HH 4096   // H
#define EE 8      // experts
#define MTOK 4096 // B*S tokens
#define MROWS 8192 // MTOK*K rows of the packed GEMM A operand

typedef __attribute__((ext_vector_type(8))) short bf16x8;
typedef __attribute__((ext_vector_type(4))) float f32x4;

__device__ __forceinline__ unsigned short f2bf(float x){
  __hip_bfloat16 h = __float2bfloat16(x);
  return *reinterpret_cast<unsigned short*>(&h);
}

__device__ __forceinline__ void gload16(const void* g, void* l){
  __builtin_amdgcn_global_load_lds((__attribute__((address_space(1))) void*)g,
                                   (__attribute__((address_space(3))) void*)l,
                                   16, 0, 0);
}

// ---------------- W -> bf16 ----------------
__global__ void cvt_w_kernel(const float4* __restrict__ W4, ushort4* __restrict__ Wb4){
  int i = blockIdx.x * 256 + threadIdx.x;   // covers H*D/4 = 1,048,576 exactly
  float4 v = W4[i];
  ushort4 o;
  o.x = f2bf(v.x); o.y = f2bf(v.y); o.z = f2bf(v.z); o.w = f2bf(v.w);
  Wb4[i] = o;
}

// ---------------- column stats of W ----------------
// 128 blocks x 256 threads; block rc covers rows [rc*32, rc*32+32),
// thread owns 4 consecutive columns via float4 row reads (coalesced).
__global__ void colstats_part_kernel(const float4* __restrict__ W4,
                                     float* __restrict__ pmean, float* __restrict__ pm2){
  int rc = blockIdx.x;          // 0..127
  int tid = threadIdx.x;        // 0..255 -> columns 4*tid..4*tid+3
  double s0=0,s1=0,s2_=0,s3=0, q0=0,q1=0,q2=0,q3=0;
  for (int h = rc * 32; h < rc * 32 + 32; ++h){
    float4 w = W4[(size_t)h * 256 + tid];
    s0 += w.x; q0 += (double)w.x * w.x;
    s1 += w.y; q1 += (double)w.y * w.y;
    s2_ += w.z; q2 += (double)w.z * w.z;
    s3 += w.w; q3 += (double)w.w * w.w;
  }
  int d0 = rc * DD + tid * 4;
  pmean[d0]   = (float)s0;  pm2[d0]   = (float)q0;
  pmean[d0+1] = (float)s1;  pm2[d0+1] = (float)q1;
  pmean[d0+2] = (float)s2_; pm2[d0+2] = (float)q2;
  pmean[d0+3] = (float)s3;  pm2[d0+3] = (float)q3;
}

__global__ void colstats_final_kernel(const float* __restrict__ pmean,
                                      const float* __restrict__ pm2,
                                      double* __restrict__ cmean, double* __restrict__ cvar){
  int d = blockIdx.x * 256 + threadIdx.x; // 4 blocks x 256
  double s = 0.0, s2 = 0.0;
  for (int c = 0; c < 128; ++c){ s += (double)pmean[c * DD + d]; s2 += (double)pm2[c * DD + d]; }
  double m = s / (double)HH;
  cmean[d] = m;
  cvar[d]  = s2 / (double)HH - m * m;  // unbiased=False variance of column d
}

__global__ void biasmean_kernel(const float* __restrict__ bias, double* __restrict__ bmean){
  __shared__ double red[256];
  double s = 0.0;
  for (int h = threadIdx.x; h < HH; h += 256) s += (double)bias[h];
  red[threadIdx.x] = s;
  __syncthreads();
  for (int k = 128; k > 0; k >>= 1){
    if (threadIdx.x < k) red[threadIdx.x] += red[threadIdx.x + k];
    __syncthreads();
  }
  if (threadIdx.x == 0) *bmean = red[0] / (double)HH;
}

// ---------------- router (f64) + build packed A operand ----------------
__global__ void router_kernel(const float* __restrict__ x,
                              const float* __restrict__ alpha,
                              const float* __restrict__ beta,
                              const double* __restrict__ cmean,
                              const double* __restrict__ cvar,
                              const double* __restrict__ bmeanp,
                              unsigned short* __restrict__ Xs,
                              float2* __restrict__ wpair){
  int t = blockIdx.x;                    // token
  const float* xt = x + (size_t)t * DD;
  int tid = threadIdx.x, lane = tid & 63, wv = tid >> 6;

  double mu[EE], s2[EE];
  #pragma unroll
  for (int e = 0; e < EE; ++e){ mu[e] = 0.0; s2[e] = 0.0; }

  float xv[4];
  #pragma unroll
  for (int r = 0; r < 4; ++r){
    int d = tid + r * 256;
    float xf = xt[d];
    xv[r] = xf;
    double xd = (double)xf, x2 = xd * xd;
    double cm = cmean[d], cv = cvar[d];
    #pragma unroll
    for (int e = 0; e < EE; ++e){
      double a = (double)alpha[e * DD + d];
      double b = (double)beta[e * DD + d];
      mu[e] += xd * (a * cm + b);
      s2[e] += x2 * (a * a * cv);
    }
  }

  // wave reduce (64 lanes)
  #pragma unroll
  for (int off = 32; off > 0; off >>= 1){
    #pragma unroll
    for (int e = 0; e < EE; ++e){
      mu[e] += __shfl_down(mu[e], off);
      s2[e] += __shfl_down(s2[e], off);
    }
  }
  __shared__ double redmu[4][EE], reds2[4][EE];
  if (lane == 0){
    #pragma unroll
    for (int e = 0; e < EE; ++e){ redmu[wv][e] = mu[e]; reds2[wv][e] = s2[e]; }
  }
  __syncthreads();

  __shared__ int se1, se2;
  if (tid == 0){
    double bm = *bmeanp;
    double lg[EE];
    #pragma unroll
    for (int e = 0; e < EE; ++e){
      double m = redmu[0][e] + redmu[1][e] + redmu[2][e] + redmu[3][e] + bm;
      double v = reds2[0][e] + reds2[1][e] + reds2[2][e] + reds2[3][e] + 1e-8;
      lg[e] = erf(m / (sqrt(2.0) * sqrt(v)));
    }
    // top-2, ties -> lower index (jax.lax.top_k semantics)
    int e1 = 0;
    for (int e = 1; e < EE; ++e) if (lg[e] > lg[e1]) e1 = e;
    int e2 = -1;
    for (int e = 0; e < EE; ++e){
      if (e == e1) continue;
      if (e2 < 0 || lg[e] > lg[e2]) e2 = e;
    }
    double ex = exp(lg[e2] - lg[e1]);        // v2 <= v1, stable softmax
    float w1 = (float)(1.0 / (1.0 + ex));
    float w2 = (float)(ex / (1.0 + ex));
    se1 = e1; se2 = e2;
    wpair[t] = make_float2(w1, w2);
  }
  __syncthreads();
  int e1 = se1, e2 = se2;

  // rows 2t, 2t+1 of packed A: x .* alpha[e1], x .* alpha[e2]  (bf16)
  #pragma unroll
  for (int r = 0; r < 4; ++r){
    int d = tid + r * 256;
    Xs[(size_t)(2 * t)     * DD + d] = f2bf(xv[r] * alpha[e1 * DD + d]);
    Xs[(size_t)(2 * t + 1) * DD + d] = f2bf(xv[r] * alpha[e2 * DD + d]);
  }
}

// ---------------- GEMM: C[8192,4096] = Xs @ Wb^T, fused relu+bias+combine ----------------
#define BM 128
#define BN 128
#define BK 32

__global__ __launch_bounds__(256) void gemm_kernel(const unsigned short* __restrict__ Xs,
                                                   const unsigned short* __restrict__ Wb,
                                                   const float* __restrict__ bias,
                                                   const float2* __restrict__ wpair,
                                                   float* __restrict__ out){
  __shared__ __align__(16) unsigned short As[BM * BK]; // 8 KB
  __shared__ __align__(16) unsigned short Bs[BN * BK]; // 8 KB

  int tid = threadIdx.x;
  int lane = tid & 63;
  int wv = tid >> 6;
  int wr = wv >> 1, wc = wv & 1;

  int bm0 = (blockIdx.x >> 5) * BM;  // 64 M-tiles
  int bn0 = (blockIdx.x & 31) * BN;  // 32 N-tiles

  // staging: each thread loads 16B; LDS linear fill
  int arow = tid >> 2;         // 0..63
  int acol = (tid & 3) * 8;    // element offset in K
  const unsigned short* Ag = Xs + (size_t)(bm0 + arow) * DD + acol;
  const unsigned short* Bg = Wb + (size_t)(bn0 + arow) * DD + acol;
  unsigned short* Asl = As + tid * 8;        // byte off = tid*16
  unsigned short* Bsl = Bs + tid * 8;

  f32x4 acc[4][4] = {};

  int l15 = lane & 15;
  int kb  = (lane >> 4) * 8;   // element offset within BK

  for (int kt = 0; kt < DD / BK; ++kt){
    int k0 = kt * BK;
    gload16(Ag + k0,            Asl);
    gload16(Ag + 64 * DD + k0,  Asl + 64 * BK);
    gload16(Bg + k0,            Bsl);
    gload16(Bg + 64 * DD + k0,  Bsl + 64 * BK);
    __syncthreads();   // drains vmcnt -> tiles ready

    bf16x8 af[4], bfr[4];
    #pragma unroll
    for (int mi = 0; mi < 4; ++mi)
      af[mi] = *(const bf16x8*)(As + (wr * 64 + mi * 16 + l15) * BK + kb);
    #pragma unroll
    for (int ni = 0; ni < 4; ++ni)
      bfr[ni] = *(const bf16x8*)(Bs + (wc * 64 + ni * 16 + l15) * BK + kb);

    #pragma unroll
    for (int mi = 0; mi < 4; ++mi)
      #pragma unroll
      for (int ni = 0; ni < 4; ++ni)
        acc[mi][ni] = __builtin_amdgcn_mfma_f32_16x16x32_bf16(af[mi], bfr[ni], acc[mi][ni], 0, 0, 0);

    __syncthreads();   // compute done before next stage overwrites
  }

  // epilogue: rows 2t (j even) and 2t+1 (j odd) are lane-local -> fuse combine
  #pragma unroll
  for (int mi = 0; mi < 4; ++mi){
    int rbase = wr * 64 + mi * 16 + ((lane >> 4) << 2);
    #pragma unroll
    for (int jp = 0; jp < 2; ++jp){
      int gm = bm0 + rbase + jp * 2;  // even
      int t = gm >> 1;
      float2 w = wpair[t];
      #pragma unroll
      for (int ni = 0; ni < 4; ++ni){
        int gh = bn0 + wc * 64 + ni * 16 + l15;
        float bz = bias[gh];
        float v0 = acc[mi][ni][jp * 2]     + bz;
        float v1 = acc[mi][ni][jp * 2 + 1] + bz;
        out[(size_t)t * HH + gh] = w.x * fmaxf(v0, 0.f) + w.y * fmaxf(v1, 0.f);
      }
    }
  }
}

extern "C" void kernel_launch(void* const* d_in, const int* in_sizes, int n_in,
                              void* d_out, int out_size, void* d_ws, size_t ws_size,
                              hipStream_t stream) {
  const float* x     = (const float*)d_in[0];
  const float* W     = (const float*)d_in[1];
  const float* bias  = (const float*)d_in[2];
  const float* alpha = (const float*)d_in[3];
  const float* beta  = (const float*)d_in[4];
  float* out = (float*)d_out;

  char* ws = (char*)d_ws;
  unsigned short* Wb = (unsigned short*)ws;                       // 8 MB
  unsigned short* Xs = (unsigned short*)(ws + (8u << 20));        // 16 MB
  float2* wpair      = (float2*)(ws + (24u << 20));               // 32 KB
  double* cmean      = (double*)(ws + (24u << 20) + (64u << 10)); // 8 KB
  double* cvar       = cmean + DD;                                // 8 KB
  double* bmean      = cvar + DD;                                 // 8 B
  float* pmean       = (float*)(ws + (24u << 20) + (128u << 10)); // 512 KB (128x1024 f32)
  float* pm2         = pmean + 128 * DD;                          // 512 KB

  cvt_w_kernel<<<4096, 256, 0, stream>>>((const float4*)W, (ushort4*)Wb);
  colstats_part_kernel<<<128, 256, 0, stream>>>((const float4*)W, pmean, pm2);
  colstats_final_kernel<<<4, 256, 0, stream>>>(pmean, pm2, cmean, cvar);
  biasmean_kernel<<<1, 256, 0, stream>>>(bias, bmean);
  router_kernel<<<MTOK, 256, 0, stream>>>(x, alpha, beta, cmean, cvar, bmean, Xs, wpair);
  gemm_kernel<<<(MROWS / BM) * (HH / BN), 256, 0, stream>>>(Xs, Wb, bias, wpair, out);
}

// Round 3
// 133.068 us; speedup vs baseline: 2.4102x; 1.5295x over previous
//
#include <hip/hip_runtime.h>
#include <hip/hip_bf16.h>
#include <math.h>

// Problem constants
#define DD 1024   // D
#define HH 4096   // H
#define EE 8      // experts
#define MTOK 4096 // B*S tokens
#define MROWS 8192 // MTOK*K rows of the packed GEMM A operand

typedef __attribute__((ext_vector_type(8))) short bf16x8;
typedef __attribute__((ext_vector_type(4))) float f32x4;

__device__ __forceinline__ unsigned short f2bf(float x){
  __hip_bfloat16 h = __float2bfloat16(x);
  return *reinterpret_cast<unsigned short*>(&h);
}

__device__ __forceinline__ void gload16(const void* g, void* l){
  __builtin_amdgcn_global_load_lds((__attribute__((address_space(1))) void*)g,
                                   (__attribute__((address_space(3))) void*)l,
                                   16, 0, 0);
}

// ---------------- W -> bf16 ----------------
__global__ void cvt_w_kernel(const float4* __restrict__ W4, ushort4* __restrict__ Wb4){
  int i = blockIdx.x * 256 + threadIdx.x;   // covers H*D/4 = 1,048,576 exactly
  float4 v = W4[i];
  ushort4 o;
  o.x = f2bf(v.x); o.y = f2bf(v.y); o.z = f2bf(v.z); o.w = f2bf(v.w);
  Wb4[i] = o;
}

// ---------------- column stats of W ----------------
__global__ void colstats_part_kernel(const float4* __restrict__ W4,
                                     float* __restrict__ pmean, float* __restrict__ pm2){
  int rc = blockIdx.x;          // 0..127
  int tid = threadIdx.x;        // 0..255 -> columns 4*tid..4*tid+3
  double s0=0,s1=0,s2_=0,s3=0, q0=0,q1=0,q2=0,q3=0;
  for (int h = rc * 32; h < rc * 32 + 32; ++h){
    float4 w = W4[(size_t)h * 256 + tid];
    s0 += w.x; q0 += (double)w.x * w.x;
    s1 += w.y; q1 += (double)w.y * w.y;
    s2_ += w.z; q2 += (double)w.z * w.z;
    s3 += w.w; q3 += (double)w.w * w.w;
  }
  int d0 = rc * DD + tid * 4;
  pmean[d0]   = (float)s0;  pm2[d0]   = (float)q0;
  pmean[d0+1] = (float)s1;  pm2[d0+1] = (float)q1;
  pmean[d0+2] = (float)s2_; pm2[d0+2] = (float)q2;
  pmean[d0+3] = (float)s3;  pm2[d0+3] = (float)q3;
}

__global__ void colstats_final_kernel(const float* __restrict__ pmean,
                                      const float* __restrict__ pm2,
                                      double* __restrict__ cmean, double* __restrict__ cvar){
  int d = blockIdx.x * 256 + threadIdx.x; // 4 blocks x 256
  double s = 0.0, s2 = 0.0;
  for (int c = 0; c < 128; ++c){ s += (double)pmean[c * DD + d]; s2 += (double)pm2[c * DD + d]; }
  double m = s / (double)HH;
  cmean[d] = m;
  cvar[d]  = s2 / (double)HH - m * m;  // unbiased=False variance of column d
}

__global__ void biasmean_kernel(const float* __restrict__ bias, double* __restrict__ bmean){
  __shared__ double red[256];
  double s = 0.0;
  for (int h = threadIdx.x; h < HH; h += 256) s += (double)bias[h];
  red[threadIdx.x] = s;
  __syncthreads();
  for (int k = 128; k > 0; k >>= 1){
    if (threadIdx.x < k) red[threadIdx.x] += red[threadIdx.x + k];
    __syncthreads();
  }
  if (threadIdx.x == 0) *bmean = red[0] / (double)HH;
}

// ---------------- precompute router projection vectors ----------------
// muw[e,d] = alpha*cmean + beta ; vw[e,d] = alpha^2 * cvar  (f32 storage)
__global__ void muvw_kernel(const float* __restrict__ alpha, const float* __restrict__ beta,
                            const double* __restrict__ cmean, const double* __restrict__ cvar,
                            float* __restrict__ muw, float* __restrict__ vw){
  int i = blockIdx.x * 256 + threadIdx.x;  // 32 blocks -> 8192
  int d = i & (DD - 1);
  double a = (double)alpha[i];
  muw[i] = (float)(a * cmean[d] + (double)beta[i]);
  vw[i]  = (float)(a * a * cvar[d]);
}

// ---------------- router: one wave per token, fused Xs build ----------------
__global__ __launch_bounds__(256) void router_kernel(const float4* __restrict__ x4,
                                                     const float4* __restrict__ alpha4,
                                                     const float4* __restrict__ muw4,
                                                     const float4* __restrict__ vw4,
                                                     const double* __restrict__ bmeanp,
                                                     unsigned short* __restrict__ Xs,
                                                     float2* __restrict__ wpair){
  int wv = threadIdx.x >> 6, lane = threadIdx.x & 63;
  int t = blockIdx.x * 4 + wv;                       // token
  const float4* xt = x4 + (size_t)t * 256;

  float4 xv[4];
  double mu[EE], s2[EE];
  #pragma unroll
  for (int e = 0; e < EE; ++e){ mu[e] = 0.0; s2[e] = 0.0; }

  #pragma unroll
  for (int r = 0; r < 4; ++r){
    int c = lane + 64 * r;                           // float4 index 0..255
    float4 xf = xt[c];
    xv[r] = xf;
    float x2x = xf.x * xf.x, x2y = xf.y * xf.y, x2z = xf.z * xf.z, x2w = xf.w * xf.w;
    #pragma unroll
    for (int e = 0; e < EE; ++e){
      float4 m4 = muw4[e * 256 + c];
      float4 v4 = vw4[e * 256 + c];
      mu[e] += (double)xf.x * m4.x + (double)xf.y * m4.y
             + (double)xf.z * m4.z + (double)xf.w * m4.w;
      s2[e] += (double)x2x * v4.x + (double)x2y * v4.y
             + (double)x2z * v4.z + (double)x2w * v4.w;
    }
  }

  // butterfly: all lanes end with totals
  #pragma unroll
  for (int off = 32; off > 0; off >>= 1){
    #pragma unroll
    for (int e = 0; e < EE; ++e){
      mu[e] += __shfl_xor(mu[e], off);
      s2[e] += __shfl_xor(s2[e], off);
    }
  }

  // rank by z = m / sqrt(2v)  (erf is monotonic -> same ordering as erf(z))
  double bm = *bmeanp;
  double z[EE];
  #pragma unroll
  for (int e = 0; e < EE; ++e){
    double m = mu[e] + bm;
    double v = s2[e] + 1e-8;
    z[e] = m / sqrt(2.0 * v);
  }
  int e1 = 0;
  #pragma unroll
  for (int e = 1; e < EE; ++e) if (z[e] > z[e1]) e1 = e;
  int e2 = -1;
  #pragma unroll
  for (int e = 0; e < EE; ++e){
    if (e == e1) continue;
    if (e2 < 0 || z[e] > z[e2]) e2 = e;
  }
  double lg1 = erf(z[e1]), lg2 = erf(z[e2]);
  double ex = exp(lg2 - lg1);                        // lg2 <= lg1
  float w1 = (float)(1.0 / (1.0 + ex));
  float w2 = (float)(ex / (1.0 + ex));
  if (lane == 0) wpair[t] = make_float2(w1, w2);

  // rows 2t, 2t+1 of packed A: x .* alpha[e1], x .* alpha[e2]  (bf16)
  const float4* a1 = alpha4 + (size_t)e1 * 256;
  const float4* a2 = alpha4 + (size_t)e2 * 256;
  ushort4* X1 = (ushort4*)(Xs + (size_t)(2 * t) * DD);
  ushort4* X2 = (ushort4*)(Xs + (size_t)(2 * t + 1) * DD);
  #pragma unroll
  for (int r = 0; r < 4; ++r){
    int c = lane + 64 * r;
    float4 xf = xv[r];
    float4 av = a1[c];
    X1[c] = make_ushort4(f2bf(xf.x * av.x), f2bf(xf.y * av.y),
                         f2bf(xf.z * av.z), f2bf(xf.w * av.w));
    av = a2[c];
    X2[c] = make_ushort4(f2bf(xf.x * av.x), f2bf(xf.y * av.y),
                         f2bf(xf.z * av.z), f2bf(xf.w * av.w));
  }
}

// ---------------- GEMM: C[8192,4096] = Xs @ Wb^T, fused relu+bias+combine ----------------
#define BM 128
#define BN 128
#define BK 32

__global__ __launch_bounds__(256) void gemm_kernel(const unsigned short* __restrict__ Xs,
                                                   const unsigned short* __restrict__ Wb,
                                                   const float* __restrict__ bias,
                                                   const float2* __restrict__ wpair,
                                                   float* __restrict__ out){
  __shared__ __align__(16) unsigned short As[BM * BK]; // 8 KB
  __shared__ __align__(16) unsigned short Bs[BN * BK]; // 8 KB

  int tid = threadIdx.x;
  int lane = tid & 63;
  int wv = tid >> 6;
  int wr = wv >> 1, wc = wv & 1;

  // XCD-aware bijective swizzle: nwg = 2048 = 8 * 256
  int bid = blockIdx.x;
  int swz = ((bid & 7) << 8) + (bid >> 3);
  int bm0 = (swz >> 5) * BM;  // 64 M-tiles
  int bn0 = (swz & 31) * BN;  // 32 N-tiles

  // staging: each thread loads 16B; LDS linear fill
  int arow = tid >> 2;         // 0..63
  int acol = (tid & 3) * 8;    // element offset in K
  const unsigned short* Ag = Xs + (size_t)(bm0 + arow) * DD + acol;
  const unsigned short* Bg = Wb + (size_t)(bn0 + arow) * DD + acol;
  unsigned short* Asl = As + tid * 8;        // byte off = tid*16
  unsigned short* Bsl = Bs + tid * 8;

  f32x4 acc[4][4] = {};

  int l15 = lane & 15;
  int kb  = (lane >> 4) * 8;   // element offset within BK

  for (int kt = 0; kt < DD / BK; ++kt){
    int k0 = kt * BK;
    gload16(Ag + k0,            Asl);
    gload16(Ag + 64 * DD + k0,  Asl + 64 * BK);
    gload16(Bg + k0,            Bsl);
    gload16(Bg + 64 * DD + k0,  Bsl + 64 * BK);
    __syncthreads();   // drains vmcnt -> tiles ready

    bf16x8 af[4], bfr[4];
    #pragma unroll
    for (int mi = 0; mi < 4; ++mi)
      af[mi] = *(const bf16x8*)(As + (wr * 64 + mi * 16 + l15) * BK + kb);
    #pragma unroll
    for (int ni = 0; ni < 4; ++ni)
      bfr[ni] = *(const bf16x8*)(Bs + (wc * 64 + ni * 16 + l15) * BK + kb);

    #pragma unroll
    for (int mi = 0; mi < 4; ++mi)
      #pragma unroll
      for (int ni = 0; ni < 4; ++ni)
        acc[mi][ni] = __builtin_amdgcn_mfma_f32_16x16x32_bf16(af[mi], bfr[ni], acc[mi][ni], 0, 0, 0);

    __syncthreads();   // compute done before next stage overwrites
  }

  // epilogue: rows 2t (j even) and 2t+1 (j odd) are lane-local -> fuse combine
  #pragma unroll
  for (int mi = 0; mi < 4; ++mi){
    int rbase = wr * 64 + mi * 16 + ((lane >> 4) << 2);
    #pragma unroll
    for (int jp = 0; jp < 2; ++jp){
      int gm = bm0 + rbase + jp * 2;  // even
      int t = gm >> 1;
      float2 w = wpair[t];
      #pragma unroll
      for (int ni = 0; ni < 4; ++ni){
        int gh = bn0 + wc * 64 + ni * 16 + l15;
        float bz = bias[gh];
        float v0 = acc[mi][ni][jp * 2]     + bz;
        float v1 = acc[mi][ni][jp * 2 + 1] + bz;
        out[(size_t)t * HH + gh] = w.x * fmaxf(v0, 0.f) + w.y * fmaxf(v1, 0.f);
      }
    }
  }
}

extern "C" void kernel_launch(void* const* d_in, const int* in_sizes, int n_in,
                              void* d_out, int out_size, void* d_ws, size_t ws_size,
                              hipStream_t stream) {
  const float* x     = (const float*)d_in[0];
  const float* W     = (const float*)d_in[1];
  const float* bias  = (const float*)d_in[2];
  const float* alpha = (const float*)d_in[3];
  const float* beta  = (const float*)d_in[4];
  float* out = (float*)d_out;

  char* ws = (char*)d_ws;
  unsigned short* Wb = (unsigned short*)ws;                       // 8 MB
  unsigned short* Xs = (unsigned short*)(ws + (8u << 20));        // 16 MB
  float2* wpair      = (float2*)(ws + (24u << 20));               // 32 KB
  double* cmean      = (double*)(ws + (24u << 20) + (64u << 10)); // 8 KB
  double* cvar       = cmean + DD;                                // 8 KB
  double* bmean      = cvar + DD;                                 // 8 B
  float* pmean       = (float*)(ws + (24u << 20) + (128u << 10)); // 512 KB
  float* pm2         = pmean + 128 * DD;                          // 512 KB
  float* muw         = (float*)(ws + (26u << 20));                // 32 KB
  float* vw          = muw + EE * DD;                             // 32 KB

  cvt_w_kernel<<<4096, 256, 0, stream>>>((const float4*)W, (ushort4*)Wb);
  colstats_part_kernel<<<128, 256, 0, stream>>>((const float4*)W, pmean, pm2);
  colstats_final_kernel<<<4, 256, 0, stream>>>(pmean, pm2, cmean, cvar);
  biasmean_kernel<<<1, 256, 0, stream>>>(bias, bmean);
  muvw_kernel<<<32, 256, 0, stream>>>(alpha, beta, cmean, cvar, muw, vw);
  router_kernel<<<MTOK / 4, 256, 0, stream>>>((const float4*)x, (const float4*)alpha,
                                              (const float4*)muw, (const float4*)vw,
                                              bmean, Xs, wpair);
  gemm_kernel<<<(MROWS / BM) * (HH / BN), 256, 0, stream>>>(Xs, Wb, bias, wpair, out);
}

// Round 4
// 124.855 us; speedup vs baseline: 2.5687x; 1.0658x over previous
//
#include <hip/hip_runtime.h>
#include <hip/hip_bf16.h>
#include <math.h>

// Problem constants
#define DD 1024   // D
#define HH 4096   // H
#define EE 8      // experts
#define MTOK 4096 // B*S tokens
#define MROWS 8192 // MTOK*K rows of the packed GEMM A operand

typedef __attribute__((ext_vector_type(8))) short bf16x8;
typedef __attribute__((ext_vector_type(4))) float f32x4;

__device__ __forceinline__ unsigned short f2bf(float x){
  __hip_bfloat16 h = __float2bfloat16(x);
  return *reinterpret_cast<unsigned short*>(&h);
}

__device__ __forceinline__ void gload16(const void* g, void* l){
  __builtin_amdgcn_global_load_lds((__attribute__((address_space(1))) void*)g,
                                   (__attribute__((address_space(3))) void*)l,
                                   16, 0, 0);
}

// ---------------- fused W->bf16 + column stats ----------------
// 128 blocks x 256 threads; block rc covers rows [rc*32, rc*32+32),
// thread owns 4 consecutive columns via float4 row reads (coalesced).
__global__ void cvtstats_kernel(const float4* __restrict__ W4, ushort4* __restrict__ Wb4,
                                float* __restrict__ pmean, float* __restrict__ pm2){
  int rc = blockIdx.x;          // 0..127
  int tid = threadIdx.x;        // 0..255 -> columns 4*tid..4*tid+3
  double s0=0,s1=0,s2_=0,s3=0, q0=0,q1=0,q2=0,q3=0;
  for (int h = rc * 32; h < rc * 32 + 32; ++h){
    float4 w = W4[(size_t)h * 256 + tid];
    Wb4[(size_t)h * 256 + tid] = make_ushort4(f2bf(w.x), f2bf(w.y), f2bf(w.z), f2bf(w.w));
    s0 += w.x; q0 += (double)w.x * w.x;
    s1 += w.y; q1 += (double)w.y * w.y;
    s2_ += w.z; q2 += (double)w.z * w.z;
    s3 += w.w; q3 += (double)w.w * w.w;
  }
  int d0 = rc * DD + tid * 4;
  pmean[d0]   = (float)s0;  pm2[d0]   = (float)q0;
  pmean[d0+1] = (float)s1;  pm2[d0+1] = (float)q1;
  pmean[d0+2] = (float)s2_; pm2[d0+2] = (float)q2;
  pmean[d0+3] = (float)s3;  pm2[d0+3] = (float)q3;
}

__global__ void colstats_final_kernel(const float* __restrict__ pmean,
                                      const float* __restrict__ pm2,
                                      double* __restrict__ cmean, double* __restrict__ cvar){
  int d = blockIdx.x * 256 + threadIdx.x; // 4 blocks x 256
  double s = 0.0, s2 = 0.0;
  for (int c = 0; c < 128; ++c){ s += (double)pmean[c * DD + d]; s2 += (double)pm2[c * DD + d]; }
  double m = s / (double)HH;
  cmean[d] = m;
  cvar[d]  = s2 / (double)HH - m * m;  // unbiased=False variance of column d
}

__global__ void biasmean_kernel(const float* __restrict__ bias, double* __restrict__ bmean){
  __shared__ double red[256];
  double s = 0.0;
  for (int h = threadIdx.x; h < HH; h += 256) s += (double)bias[h];
  red[threadIdx.x] = s;
  __syncthreads();
  for (int k = 128; k > 0; k >>= 1){
    if (threadIdx.x < k) red[threadIdx.x] += red[threadIdx.x + k];
    __syncthreads();
  }
  if (threadIdx.x == 0) *bmean = red[0] / (double)HH;
}

// ---------------- precompute router projection vectors ----------------
__global__ void muvw_kernel(const float* __restrict__ alpha, const float* __restrict__ beta,
                            const double* __restrict__ cmean, const double* __restrict__ cvar,
                            float* __restrict__ muw, float* __restrict__ vw){
  int i = blockIdx.x * 256 + threadIdx.x;  // 32 blocks -> 8192
  int d = i & (DD - 1);
  double a = (double)alpha[i];
  muw[i] = (float)(a * cmean[d] + (double)beta[i]);
  vw[i]  = (float)(a * a * cvar[d]);
}

// ---------------- router: one wave per token, fused Xs build ----------------
__global__ __launch_bounds__(256) void router_kernel(const float4* __restrict__ x4,
                                                     const float4* __restrict__ alpha4,
                                                     const float4* __restrict__ muw4,
                                                     const float4* __restrict__ vw4,
                                                     const double* __restrict__ bmeanp,
                                                     unsigned short* __restrict__ Xs,
                                                     float2* __restrict__ wpair){
  int wv = threadIdx.x >> 6, lane = threadIdx.x & 63;
  int t = blockIdx.x * 4 + wv;                       // token
  const float4* xt = x4 + (size_t)t * 256;

  float4 xv[4];
  double mu[EE], s2[EE];
  #pragma unroll
  for (int e = 0; e < EE; ++e){ mu[e] = 0.0; s2[e] = 0.0; }

  #pragma unroll
  for (int r = 0; r < 4; ++r){
    int c = lane + 64 * r;                           // float4 index 0..255
    float4 xf = xt[c];
    xv[r] = xf;
    float x2x = xf.x * xf.x, x2y = xf.y * xf.y, x2z = xf.z * xf.z, x2w = xf.w * xf.w;
    #pragma unroll
    for (int e = 0; e < EE; ++e){
      float4 m4 = muw4[e * 256 + c];
      float4 v4 = vw4[e * 256 + c];
      mu[e] += (double)xf.x * m4.x + (double)xf.y * m4.y
             + (double)xf.z * m4.z + (double)xf.w * m4.w;
      s2[e] += (double)x2x * v4.x + (double)x2y * v4.y
             + (double)x2z * v4.z + (double)x2w * v4.w;
    }
  }

  #pragma unroll
  for (int off = 32; off > 0; off >>= 1){
    #pragma unroll
    for (int e = 0; e < EE; ++e){
      mu[e] += __shfl_xor(mu[e], off);
      s2[e] += __shfl_xor(s2[e], off);
    }
  }

  // rank by z = m / sqrt(2v)  (erf is monotonic)
  double bm = *bmeanp;
  double z[EE];
  #pragma unroll
  for (int e = 0; e < EE; ++e){
    double m = mu[e] + bm;
    double v = s2[e] + 1e-8;
    z[e] = m / sqrt(2.0 * v);
  }
  int e1 = 0;
  #pragma unroll
  for (int e = 1; e < EE; ++e) if (z[e] > z[e1]) e1 = e;
  int e2 = -1;
  #pragma unroll
  for (int e = 0; e < EE; ++e){
    if (e == e1) continue;
    if (e2 < 0 || z[e] > z[e2]) e2 = e;
  }
  double lg1 = erf(z[e1]), lg2 = erf(z[e2]);
  double ex = exp(lg2 - lg1);                        // lg2 <= lg1
  float w1 = (float)(1.0 / (1.0 + ex));
  float w2 = (float)(ex / (1.0 + ex));
  if (lane == 0) wpair[t] = make_float2(w1, w2);

  const float4* a1 = alpha4 + (size_t)e1 * 256;
  const float4* a2 = alpha4 + (size_t)e2 * 256;
  ushort4* X1 = (ushort4*)(Xs + (size_t)(2 * t) * DD);
  ushort4* X2 = (ushort4*)(Xs + (size_t)(2 * t + 1) * DD);
  #pragma unroll
  for (int r = 0; r < 4; ++r){
    int c = lane + 64 * r;
    float4 xf = xv[r];
    float4 av = a1[c];
    X1[c] = make_ushort4(f2bf(xf.x * av.x), f2bf(xf.y * av.y),
                         f2bf(xf.z * av.z), f2bf(xf.w * av.w));
    av = a2[c];
    X2[c] = make_ushort4(f2bf(xf.x * av.x), f2bf(xf.y * av.y),
                         f2bf(xf.z * av.z), f2bf(xf.w * av.w));
  }
}

// ---------------- GEMM: C[8192,4096] = Xs @ Wb^T, fused relu+bias+combine ----------------
// 128x128 tile, BK=64, double-buffered LDS with counted vmcnt (loads in flight
// across raw s_barriers), XOR-swizzled LDS (chunk ^= row&7) via pre-swizzled
// global source (rule #21), setprio around MFMA cluster.
#define BM 128
#define BN 128
#define BKT 64
#define NKT (DD / BKT)   // 16

__global__ __launch_bounds__(256, 2) void gemm_kernel(const unsigned short* __restrict__ Xs,
                                                      const unsigned short* __restrict__ Wb,
                                                      const float* __restrict__ bias,
                                                      const float2* __restrict__ wpair,
                                                      float* __restrict__ out){
  // slot = 128 rows x 64 bf16 = 16KB ; 2 slots per operand -> 64KB total
  __shared__ __align__(16) unsigned short As[2 * 8192];
  __shared__ __align__(16) unsigned short Bs[2 * 8192];

  int tid = threadIdx.x, lane = tid & 63, wv = tid >> 6;
  int wr = wv >> 1, wc = wv & 1;
  int l15 = lane & 15;

  // XCD-aware swizzle: 2048 blocks = 8 chunks x 256; chunk owns 8 M-tiles x all 32 N-tiles
  int bid = blockIdx.x;
  int ch = bid & 7, local = bid >> 3;       // ch: XCD chunk, local 0..255
  int mtile = ch * 8 + (local & 7);
  int ntile = local >> 3;                   // 0..31
  int bm0 = mtile * BM, bn0 = ntile * BN;

  // --- staging addresses (pre-swizzled global source; LDS fill is linear) ---
  // wave loads rows 32*wv .. 32*wv+31 (4 loads x 8 rows); lane covers row rl, K-chunk cg
  int rl = lane >> 3;                       // 0..7 row within 8-row group
  int cg = (lane & 7) ^ rl;                 // swizzled global 16B-chunk (involution)
  const unsigned short* gA = Xs + (size_t)(bm0 + 32 * wv + rl) * DD + cg * 8;
  const unsigned short* gB = Wb + (size_t)(bn0 + 32 * wv + rl) * DD + cg * 8;

  // --- LDS read positions (apply same XOR on read) ---
  int posr0 = (lane >> 4) ^ (l15 & 7);        // ks=0: chunk (l>>4)
  int posr1 = (4 + (lane >> 4)) ^ (l15 & 7);  // ks=1: chunk 4+(l>>4)

  f32x4 acc[4][4] = {};

  auto stage = [&](int kt, int slot){
    int koff = kt * BKT;
    #pragma unroll
    for (int j = 0; j < 4; ++j){
      gload16(gA + (size_t)(8 * j) * DD + koff, (void*)(As + slot * 8192 + (4 * wv + j) * 512));
      gload16(gB + (size_t)(8 * j) * DD + koff, (void*)(Bs + slot * 8192 + (4 * wv + j) * 512));
    }
  };

  stage(0, 0);
  for (int t = 0; t < NKT; ++t){
    if (t < NKT - 1){
      stage(t + 1, (t + 1) & 1);
      asm volatile("s_waitcnt vmcnt(8)" ::: "memory");  // tile t resident; next tile in flight
    } else {
      asm volatile("s_waitcnt vmcnt(0)" ::: "memory");
    }
    __builtin_amdgcn_s_barrier();                        // all waves see tile t

    const unsigned short* Ab = As + (t & 1) * 8192;
    const unsigned short* Bb = Bs + (t & 1) * 8192;
    bf16x8 a0[4], a1[4], b0[4], b1[4];
    #pragma unroll
    for (int i = 0; i < 4; ++i){
      int ra = (wr * 64 + i * 16 + l15) * 64;
      a0[i] = *(const bf16x8*)(Ab + ra + posr0 * 8);
      a1[i] = *(const bf16x8*)(Ab + ra + posr1 * 8);
      int rb = (wc * 64 + i * 16 + l15) * 64;
      b0[i] = *(const bf16x8*)(Bb + rb + posr0 * 8);
      b1[i] = *(const bf16x8*)(Bb + rb + posr1 * 8);
    }

    __builtin_amdgcn_s_setprio(1);
    #pragma unroll
    for (int mi = 0; mi < 4; ++mi)
      #pragma unroll
      for (int ni = 0; ni < 4; ++ni){
        acc[mi][ni] = __builtin_amdgcn_mfma_f32_16x16x32_bf16(a0[mi], b0[ni], acc[mi][ni], 0, 0, 0);
        acc[mi][ni] = __builtin_amdgcn_mfma_f32_16x16x32_bf16(a1[mi], b1[ni], acc[mi][ni], 0, 0, 0);
      }
    __builtin_amdgcn_s_setprio(0);

    asm volatile("s_waitcnt lgkmcnt(0)" ::: "memory");   // all ds_reads of this slot done
    __builtin_amdgcn_s_barrier();                        // before next iter's stage overwrites
  }

  // epilogue: rows 2t (j even) and 2t+1 (j odd) are lane-local -> fuse combine
  #pragma unroll
  for (int mi = 0; mi < 4; ++mi){
    int rbase = wr * 64 + mi * 16 + ((lane >> 4) << 2);
    #pragma unroll
    for (int jp = 0; jp < 2; ++jp){
      int gm = bm0 + rbase + jp * 2;  // even
      int t = gm >> 1;
      float2 w = wpair[t];
      #pragma unroll
      for (int ni = 0; ni < 4; ++ni){
        int gh = bn0 + wc * 64 + ni * 16 + l15;
        float bz = bias[gh];
        float v0 = acc[mi][ni][jp * 2]     + bz;
        float v1 = acc[mi][ni][jp * 2 + 1] + bz;
        out[(size_t)t * HH + gh] = w.x * fmaxf(v0, 0.f) + w.y * fmaxf(v1, 0.f);
      }
    }
  }
}

extern "C" void kernel_launch(void* const* d_in, const int* in_sizes, int n_in,
                              void* d_out, int out_size, void* d_ws, size_t ws_size,
                              hipStream_t stream) {
  const float* x     = (const float*)d_in[0];
  const float* W     = (const float*)d_in[1];
  const float* bias  = (const float*)d_in[2];
  const float* alpha = (const float*)d_in[3];
  const float* beta  = (const float*)d_in[4];
  float* out = (float*)d_out;

  char* ws = (char*)d_ws;
  unsigned short* Wb = (unsigned short*)ws;                       // 8 MB
  unsigned short* Xs = (unsigned short*)(ws + (8u << 20));        // 16 MB
  float2* wpair      = (float2*)(ws + (24u << 20));               // 32 KB
  double* cmean      = (double*)(ws + (24u << 20) + (64u << 10)); // 8 KB
  double* cvar       = cmean + DD;                                // 8 KB
  double* bmean      = cvar + DD;                                 // 8 B
  float* pmean       = (float*)(ws + (24u << 20) + (128u << 10)); // 512 KB
  float* pm2         = pmean + 128 * DD;                          // 512 KB
  float* muw         = (float*)(ws + (26u << 20));                // 32 KB
  float* vw          = muw + EE * DD;                             // 32 KB

  cvtstats_kernel<<<128, 256, 0, stream>>>((const float4*)W, (ushort4*)Wb, pmean, pm2);
  colstats_final_kernel<<<4, 256, 0, stream>>>(pmean, pm2, cmean, cvar);
  biasmean_kernel<<<1, 256, 0, stream>>>(bias, bmean);
  muvw_kernel<<<32, 256, 0, stream>>>(alpha, beta, cmean, cvar, muw, vw);
  router_kernel<<<MTOK / 4, 256, 0, stream>>>((const float4*)x, (const float4*)alpha,
                                              (const float4*)muw, (const float4*)vw,
                                              bmean, Xs, wpair);
  gemm_kernel<<<(MROWS / BM) * (HH / BN), 256, 0, stream>>>(Xs, Wb, bias, wpair, out);
}